// Round 14
// baseline (69.722 us; speedup 1.0000x reference)
//
#include <hip/hip_runtime.h>

typedef unsigned short ushort_t;
typedef __attribute__((ext_vector_type(8))) __bf16 bf16x8;
typedef __attribute__((ext_vector_type(8))) short short8_t;
typedef __attribute__((ext_vector_type(4))) short short4_t;
typedef __attribute__((ext_vector_type(4))) float f32x4;

#define C127 (127.0f / 128.0f)

__device__ inline ushort_t f2bf(float f) {
  unsigned u = __builtin_bit_cast(unsigned, f);
  u += 0x7fffu + ((u >> 16) & 1u);
  return (ushort_t)(u >> 16);
}
__device__ inline float bf2f(ushort_t v) {
  return __builtin_bit_cast(float, (unsigned)v << 16);
}
__device__ inline bf16x8 ldfrag(const ushort_t* p) {
  return __builtin_bit_cast(bf16x8, *(const short8_t*)p);
}
__device__ inline f32x4 mfma16(bf16x8 a, bf16x8 b, f32x4 c) {
  return __builtin_amdgcn_mfma_f32_16x16x32_bf16(a, b, c, 0, 0, 0);
}
// (row,col) in a 64-wide swizzled tile (64-row)
__device__ inline int swz(int row, int col) {
  return row * 64 + (col ^ ((row & 7) << 3));
}
// logical (r<64, k<32) in a 2048e tile stored 32x64 (row-halves interleaved)
__device__ inline int rd32(int r, int k) {
  return (r & 31) * 64 + ((k + 32 * (r >> 5)) ^ (((r & 31) & 7) << 3));
}
// (row<64, col<128) in 64x128 swizzled stash
__device__ inline int swz128(int row, int col) {
  return row * 128 + ((col & 64) | ((col & 63) ^ ((row & 7) << 3)));
}
__device__ inline void gl_lds16(const ushort_t* g, ushort_t* l) {
  __builtin_amdgcn_global_load_lds(
      (const __attribute__((address_space(1))) unsigned*)(g),
      (__attribute__((address_space(3))) unsigned*)(l),
      16, 0, 0);
}

// ================= prep: fully vectorized (16B per thread) =================
// wft:   per s: [8 gp][4 wid][nk32][2048e 32x64-interleaved]
//        wid<2 -> t1 cols (gp*2+wid)*64.. ; wid>=2 -> t2 cols 1024+(gp*2+wid-2)*64..
// xbt32: [64 rb(64rows)][24 kt32][2048e 32x64-interleaved]
// xbt64: [32 rowblk128][12 kblk][128x64 swz]   (k_out)
// bfm:   [8 nb][14 kblk][32x64 swz] ; w1b row-major [4][16][1024]
__global__ __launch_bounds__(256) void k_prep(
    const float* __restrict__ x,
    const float* Wp, const float* Wmi, const float* Wma, const float* Wd,
    const float* W1p, const float* W1mi, const float* W1ma, const float* W1d,
    const float* Wop, const float* Womi, const float* Woma, const float* Wod,
    const float* bop, const float* bomi, const float* boma, const float* bod,
    const float* Wc,
    ushort_t* wft, ushort_t* xbt32, ushort_t* xbt64, ushort_t* bfm,
    ushort_t* w1b, float* biassum)
{
  int i = blockIdx.x * 256 + threadIdx.x;
  const int RW = 294912, RX32 = RW + 393216, RX64 = RX32 + 393216,
            RB = RX64 + 28672, R1 = RB + 8192, RE = R1 + 32;
  if (i < RW) {
    const float* src; int base, d, nk32;
    if (i < 32768)       { base = 0;      d = 128; nk32 = 4;  src = Wp; }
    else if (i < 98304)  { base = 32768;  d = 256; nk32 = 8;  src = Wmi; }
    else if (i < 196608) { base = 98304;  d = 384; nk32 = 12; src = Wma; }
    else                 { base = 196608; d = 384; nk32 = 12; src = Wd; }
    int u = i - base;
    int T = u >> 8, e0 = (u & 255) * 8;
    int erow = e0 >> 6, c0 = e0 & 63;
    int q = c0 ^ ((erow & 7) << 3);
    int whalf = q >> 5, k0 = q & 31;
    int kt = T % nk32, rem = T / nk32;     // rem = gp*4 + wid
    int wd = rem & 3, gp = rem >> 2;
    int wl = whalf * 32 + erow;
    int wcol = (wd < 2) ? (gp * 2 + wd) * 64 + wl
                        : 1024 + (gp * 2 + wd - 2) * 64 + wl;
    const float* sp = src + (size_t)wcol * d + kt * 32 + k0;
    ushort_t tmp[8];
#pragma unroll
    for (int e = 0; e < 8; ++e) tmp[e] = f2bf(sp[e]);
    *(short8_t*)(wft + (size_t)i * 8) = *(const short8_t*)tmp;
  } else if (i < RX32) {
    int u = i - RW;
    int T = u >> 8, e0 = (u & 255) * 8;
    int erow = e0 >> 6, c0 = e0 & 63;
    int q = c0 ^ ((erow & 7) << 3);
    int rhalf = q >> 5, k0 = q & 31;
    int rb = T / 24, kt = T - rb * 24;
    int row = rb * 64 + rhalf * 32 + erow;
    const float* sp = x + (size_t)row * 768 + kt * 32 + k0;
    ushort_t tmp[8];
#pragma unroll
    for (int e = 0; e < 8; ++e) tmp[e] = f2bf(sp[e]);
    *(short8_t*)(xbt32 + (size_t)u * 8) = *(const short8_t*)tmp;
  } else if (i < RX64) {
    int u = i - RX32;
    int tile = u >> 10, trow = (u & 1023) >> 3, scol0 = (u & 7) * 8;
    int rowblk = tile / 12, kblk = tile - rowblk * 12;
    int col0 = scol0 ^ ((trow & 7) << 3);
    const float* sp = x + (size_t)(rowblk * 128 + trow) * 768 + kblk * 64 + col0;
    ushort_t tmp[8];
#pragma unroll
    for (int e = 0; e < 8; ++e) tmp[e] = f2bf(sp[e]);
    *(short8_t*)(xbt64 + (size_t)u * 8) = *(const short8_t*)tmp;
  } else if (i < RB) {
    int i3 = i - RX64;
    int tile = i3 >> 8, trow = (i3 & 255) >> 3, scol0 = (i3 & 7) * 8;
    int nb = tile / 14, kblk = tile - nb * 14;
    int col0 = scol0 ^ ((trow & 7) << 3);
    int n = nb * 32 + trow, c0 = kblk * 64 + col0;
    const float* sp;
    if (c0 < 128) {
      int ss = c0 >> 5, jj = c0 & 31;
      const float* src = (ss == 0) ? Wop : (ss == 1) ? Womi : (ss == 2) ? Woma : Wod;
      sp = src + n * 32 + jj;
    } else {
      sp = Wc + n * 768 + (c0 - 128);
    }
    ushort_t tmp[8];
#pragma unroll
    for (int e = 0; e < 8; ++e) tmp[e] = f2bf(sp[e]);
    *(short8_t*)(bfm + (size_t)i3 * 8) = *(const short8_t*)tmp;
  } else if (i < R1) {
    int i4 = i - RB;
    int s = i4 >> 11, r = i4 & 2047;
    const float* src = (s == 0) ? W1p : (s == 1) ? W1mi : (s == 2) ? W1ma : W1d;
    ushort_t tmp[8];
#pragma unroll
    for (int e = 0; e < 8; ++e) tmp[e] = f2bf(src[r * 8 + e]);
    *(short8_t*)(w1b + (size_t)i4 * 8) = *(const short8_t*)tmp;
  } else if (i < RE) {
    int i5 = i - R1;
#pragma unroll
    for (int e = 0; e < 8; ++e) {
      int n = i5 * 8 + e;
      biassum[n] = bop[n] + bomi[n] + boma[n] + bod[n];
    }
  }
}

// == ft GEMM: 64x256 block, 4 waves of 64x64, BK=32, dbuf, chained 4-s jobs ==
struct FtP {
  const ushort_t* xbt32;
  const ushort_t* wft;
  const ushort_t* w1b;
  float* pf;   // [4 s * 16 g][4096 rows][16 j]
  const float* bft0; const float* bft1; const float* bft2; const float* bft3;
};

__global__ __launch_bounds__(256, 2) void k_ft(FtP p) {
  int bid = blockIdx.x;
  // XCD-aware swizzle (512 = 8 XCD * 64)
  int w = (bid & 7) * 64 + (bid >> 3);
  int gp = w & 7, rowblk = w >> 3;        // gp 0..7, rowblk 0..63 (64 rows)
  int row0 = rowblk * 64;
  int g0 = gp * 2;
  int tid = threadIdx.x, lane = tid & 63, wid = tid >> 6;   // 4 waves
  int lr = lane & 15, lk = (lane >> 4) * 8, lrow = (lane >> 4) * 4;

  __shared__ ushort_t lA[2][2048];   // A 64x32, dbuf (4 KB each)
  __shared__ ushort_t lB[2][8192];   // B 256colsx32k (4 quads), dbuf (16 KB each)

  const int S_ORD[4] = {2, 3, 1, 0};
  const int NK32[4] = {4, 8, 12, 12};
  const int SOFF[4] = {0, 262144, 786432, 1572864};
  const unsigned long long CT[4] = {0x60ULL, 0x8721ULL, 0xBA9543ULL, 0xBA8542ULL};
  const float* BFT[4] = {p.bft0, p.bft1, p.bft2, p.bft3};

#define STG(bufi, s_, ks_)                                                   \
  {                                                                          \
    int ch_ = (int)((CT[s_] >> (4 * ((ks_) >> 1))) & 15ULL);                 \
    int kt_ = ch_ * 2 + ((ks_) & 1);                                         \
    const ushort_t* at_ = p.xbt32 + ((size_t)(rowblk * 24 + kt_)) * 2048;    \
    const ushort_t* bt_ = p.wft + SOFF[s_] +                                 \
        ((size_t)((gp * 4 + wid) * NK32[s_] + (ks_))) * 2048;                \
    gl_lds16(at_ + wid * 512 + lane * 8, &lA[bufi][wid * 512]);              \
    _Pragma("unroll") for (int c = 0; c < 4; ++c)                            \
      gl_lds16(bt_ + c * 512 + lane * 8, &lB[bufi][wid * 2048 + c * 512]);   \
  }

  int cur = 0;
  STG(0, 2, 0);   // first job's tile 0

#pragma unroll
  for (int jj = 0; jj < 4; ++jj) {
    const int s = S_ORD[jj];
    const int nk = NK32[s];
    const float* bft = BFT[s];

    f32x4 acc[4][4];
#pragma unroll
    for (int m = 0; m < 4; ++m)
#pragma unroll
      for (int n = 0; n < 4; ++n) acc[m][n] = (f32x4){0.f, 0.f, 0.f, 0.f};

    for (int t = 0; t < nk; ++t) {
      asm volatile("s_waitcnt vmcnt(0)" ::: "memory");
      __builtin_amdgcn_sched_barrier(0);
      __builtin_amdgcn_s_barrier();
      if (t + 1 < nk) {
        STG(cur ^ 1, s, t + 1);
      } else if (jj < 3) {
        const int sn = S_ORD[jj + 1];
        STG(cur ^ 1, sn, 0);
      }
      bf16x8 a[4], bb[4];
#pragma unroll
      for (int m = 0; m < 4; ++m)
        a[m] = ldfrag(&lA[cur][rd32(m * 16 + lr, lk)]);
#pragma unroll
      for (int n = 0; n < 4; ++n)
        bb[n] = ldfrag(&lB[cur][wid * 2048 + rd32(n * 16 + lr, lk)]);
      __builtin_amdgcn_s_setprio(1);
#pragma unroll
      for (int m = 0; m < 4; ++m)
#pragma unroll
        for (int n = 0; n < 4; ++n)
          acc[m][n] = mfma16(a[m], bb[n], acc[m][n]);
      __builtin_amdgcn_s_setprio(0);
      cur ^= 1;
    }

    // ---- epilogue: nk even -> cur==0; buf1 free (next job's t0 -> buf0).
    // stash/act in lB[1] (16 KB): t2 waves stash, t1 waves overwrite in place.
    __builtin_amdgcn_s_barrier();
    ushort_t* stash = &lB[1][0];
    if (wid >= 2) {
      int gq = wid - 2;
      const float* b2p = bft + 1024 + (g0 + gq) * 64;
#pragma unroll
      for (int m = 0; m < 4; ++m)
#pragma unroll
        for (int n = 0; n < 4; ++n) {
          int col = gq * 64 + n * 16 + lr;
          float b2 = b2p[n * 16 + lr];
#pragma unroll
          for (int r = 0; r < 4; ++r) {
            int row = m * 16 + lrow + r;
            stash[swz128(row, col)] = f2bf(acc[m][n][r] + b2);
          }
        }
    }
    asm volatile("s_waitcnt lgkmcnt(0)" ::: "memory");
    __builtin_amdgcn_sched_barrier(0);
    __builtin_amdgcn_s_barrier();
    if (wid < 2) {
      const float* b1p = bft + (g0 + wid) * 64;
#pragma unroll
      for (int m = 0; m < 4; ++m)
#pragma unroll
        for (int n = 0; n < 4; ++n) {
          int col = wid * 64 + n * 16 + lr;
          float b1 = b1p[n * 16 + lr];
#pragma unroll
          for (int r = 0; r < 4; ++r) {
            int row = m * 16 + lrow + r;
            int idx = swz128(row, col);
            float v = (acc[m][n][r] + b1) * bf2f(stash[idx]) * C127;
            stash[idx] = f2bf(v);
          }
        }
    }
    asm volatile("s_waitcnt lgkmcnt(0)" ::: "memory");
    __builtin_amdgcn_sched_barrier(0);
    __builtin_amdgcn_s_barrier();

    // fused W1: wave wid handles rows wid*16..+15 for both g's of the pair
#pragma unroll
    for (int gg = 0; gg < 2; ++gg) {
      int g = g0 + gg;
      const ushort_t* w1base = p.w1b + s * 16384 + lr * 1024 + g * 64;
      f32x4 facc = {0.f, 0.f, 0.f, 0.f};
#pragma unroll
      for (int kk2 = 0; kk2 < 2; ++kk2) {
        bf16x8 af =
            ldfrag(&stash[swz128(wid * 16 + lr, gg * 64 + kk2 * 32 + lk)]);
        bf16x8 bw = ldfrag(w1base + kk2 * 32 + lk);
        facc = mfma16(af, bw, facc);
      }
      float* pfp = p.pf +
          ((size_t)(s * 16 + g) * 4096 + row0 + wid * 16 + lrow) * 16 + lr;
#pragma unroll
      for (int r = 0; r < 4; ++r) pfp[r * 16] = facc[r];
    }
    // no trailing barrier: W1 ds_reads are consumed (lgkmcnt-waited by MFMA)
    // before this wave reaches the next loop-top barrier.
  }
#undef STG
}

// ============ reduce 16 partials -> cat (vectorized float4/short4) ============
__global__ __launch_bounds__(256) void k_fin(
    const float* __restrict__ pf, ushort_t* __restrict__ cat_t,
    const float* b1p, const float* b1mi, const float* b1ma, const float* b1d)
{
  int tid = threadIdx.x;
  int q = tid & 3, s = (tid >> 2) & 3, rl = tid >> 4;   // 4 x 4 x 16
  int row = blockIdx.x * 16 + rl;
  int j0 = q * 4;
  const float* b1 = (s == 0) ? b1p : (s == 1) ? b1mi : (s == 2) ? b1ma : b1d;
  f32x4 acc = {0.f, 0.f, 0.f, 0.f};
  const float* base = pf + ((size_t)(s * 16) * 4096 + row) * 16 + j0;
#pragma unroll
  for (int g = 0; g < 16; ++g) {
    f32x4 v = *(const f32x4*)(base + (size_t)g * 65536);
    acc += v;
  }
  ushort_t c4f[4], c4s[4];
#pragma unroll
  for (int e = 0; e < 4; ++e) {
    float f = acc[e] + b1[j0 + e];
    c4f[e] = f2bf(fminf(fmaxf(f, 0.f), 1.f));
    c4s[e] = f2bf(fminf(f * f * C127, 1.f));
  }
  int rb = row >> 6, trow = row & 63;
  int c1 = s * 32 + j0;
  {
    int kc = c1 >> 6, tc = (c1 & 63) ^ ((trow & 7) << 3);
    *(short4_t*)&cat_t[(size_t)(rb * 2 + kc) * 4096 + trow * 64 + tc] =
        *(const short4_t*)c4f;
  }
  {
    int c2 = c1 + 16;
    int kc = c2 >> 6, tc = (c2 & 63) ^ ((trow & 7) << 3);
    *(short4_t*)&cat_t[(size_t)(rb * 2 + kc) * 4096 + trow * 64 + tc] =
        *(const short4_t*)c4s;
  }
}

// ======== final GEMM: 64-row blocks, 3-deep pipeline, counted vmcnt ========
__global__ __launch_bounds__(256) void k_out(
    const ushort_t* __restrict__ cat_t, const ushort_t* __restrict__ xbt,
    const ushort_t* __restrict__ bfm, const float* __restrict__ biassum,
    float* __restrict__ out)
{
  int bid = blockIdx.y * 8 + blockIdx.x;
  int w = (bid & 7) * 64 + (bid >> 3);
  int nb = w & 7, rowblk = w >> 3;
  int tid = threadIdx.x, lane = tid & 63, wid = tid >> 6;
  int lr = lane & 15, lk = (lane >> 4) * 8, lrow = (lane >> 4) * 4;

  __shared__ ushort_t lA[3][4096];
  __shared__ ushort_t lB[3][2048];

  f32x4 acc[2];
  acc[0] = (f32x4){0.f, 0.f, 0.f, 0.f};
  acc[1] = (f32x4){0.f, 0.f, 0.f, 0.f};

#define STGO(bufi, kb_)                                                       \
  {                                                                           \
    int kb__ = (kb_);                                                         \
    const ushort_t* at = (kb__ < 2)                                           \
        ? cat_t + ((size_t)rowblk * 2 + kb__) * 4096                          \
        : xbt + ((size_t)(rowblk >> 1) * 12 + (kb__ - 2)) * 8192 +            \
              (rowblk & 1) * 4096;                                            \
    const ushort_t* bt = bfm + ((size_t)nb * 14 + kb__) * 2048;               \
    _Pragma("unroll") for (int c = 0; c < 2; ++c) {                           \
      int off = (c * 4 + wid) * 512;                                          \
      gl_lds16(at + off + lane * 8, &lA[bufi][off]);                          \
    }                                                                         \
    { int off = wid * 512; gl_lds16(bt + off + lane * 8, &lB[bufi][off]); }   \
  }

  STGO(0, 0);
  STGO(1, 1);
  for (int kb = 0; kb < 14; ++kb) {
    int cur = kb % 3;
    if (kb + 1 < 14) {
      asm volatile("s_waitcnt vmcnt(3)" ::: "memory");
    } else {
      asm volatile("s_waitcnt vmcnt(0)" ::: "memory");
    }
    __builtin_amdgcn_sched_barrier(0);
    __builtin_amdgcn_s_barrier();
    if (kb + 2 < 14) STGO((kb + 2) % 3, kb + 2);
#pragma unroll
    for (int kk = 0; kk < 64; kk += 32) {
      bf16x8 b0 = ldfrag(&lB[cur][swz(lr, kk + lk)]);
      bf16x8 b1v = ldfrag(&lB[cur][swz(16 + lr, kk + lk)]);
      bf16x8 a = ldfrag(&lA[cur][swz(wid * 16 + lr, kk + lk)]);
      __builtin_amdgcn_s_setprio(1);
      acc[0] = mfma16(a, b0, acc[0]);
      acc[1] = mfma16(a, b1v, acc[1]);
      __builtin_amdgcn_s_setprio(0);
    }
  }
#undef STGO

#pragma unroll
  for (int n = 0; n < 2; ++n) {
    int col = nb * 32 + n * 16 + lr;
    float bs = biassum[col];
#pragma unroll
    for (int r = 0; r < 4; ++r) {
      int row = rowblk * 64 + wid * 16 + lrow + r;
      out[(size_t)row * 256 + col] = acc[n][r] + bs;
    }
  }
}

extern "C" void kernel_launch(void* const* d_in, const int* in_sizes, int n_in,
                              void* d_out, int out_size, void* d_ws, size_t ws_size,
                              hipStream_t stream)
{
  const float* x     = (const float*)d_in[0];
  const float* pWft  = (const float*)d_in[5];   const float* pbft  = (const float*)d_in[6];
  const float* pW1   = (const float*)d_in[7];   const float* pb1   = (const float*)d_in[8];
  const float* pWo   = (const float*)d_in[9];   const float* pbo   = (const float*)d_in[10];
  const float* miWft = (const float*)d_in[11];  const float* mibft = (const float*)d_in[12];
  const float* miW1  = (const float*)d_in[13];  const float* mib1  = (const float*)d_in[14];
  const float* miWo  = (const float*)d_in[15];  const float* mibo  = (const float*)d_in[16];
  const float* maWft = (const float*)d_in[17];  const float* mabft = (const float*)d_in[18];
  const float* maW1  = (const float*)d_in[19];  const float* mab1  = (const float*)d_in[20];
  const float* maWo  = (const float*)d_in[21];  const float* mabo  = (const float*)d_in[22];
  const float* dWft  = (const float*)d_in[23];  const float* dbft  = (const float*)d_in[24];
  const float* dW1   = (const float*)d_in[25];  const float* db1   = (const float*)d_in[26];
  const float* dWo   = (const float*)d_in[27];  const float* dbo   = (const float*)d_in[28];
  const float* Wc    = (const float*)d_in[29];

  char* wsb = (char*)d_ws;
  ushort_t* xbt32   = (ushort_t*)(wsb + 0);          //  6,291,456
  ushort_t* xbt64   = (ushort_t*)(wsb + 6291456);    //  6,291,456
  ushort_t* wft     = (ushort_t*)(wsb + 12582912);   //  4,718,592
  ushort_t* w1b     = (ushort_t*)(wsb + 17301504);   //    131,072
  ushort_t* bfm     = (ushort_t*)(wsb + 17432576);   //    458,752
  float*    biassum = (float*)(wsb + 17891328);      //      1,024
  float*    pf      = (float*)(wsb + 17892352);      // 16,777,216
  ushort_t* cat_t   = (ushort_t*)(wsb + 34669568);   //  1,048,576

  k_prep<<<dim3(4369), dim3(256), 0, stream>>>(
      x, pWft, miWft, maWft, dWft, pW1, miW1, maW1, dW1,
      pWo, miWo, maWo, dWo, pbo, mibo, mabo, dbo, Wc,
      wft, xbt32, xbt64, bfm, w1b, biassum);

  FtP fp;
  fp.xbt32 = xbt32; fp.wft = wft; fp.w1b = w1b; fp.pf = pf;
  fp.bft0 = pbft; fp.bft1 = mibft; fp.bft2 = mabft; fp.bft3 = dbft;
  k_ft<<<dim3(512), dim3(256), 0, stream>>>(fp);

  k_fin<<<dim3(256), dim3(256), 0, stream>>>(pf, cat_t, pb1, mib1, mab1, db1);

  k_out<<<dim3(8, 64), dim3(256), 0, stream>>>(cat_t, xbt64, bfm, biassum, (float*)d_out);
}

// Round 15
// 51.639 us; speedup vs baseline: 1.3502x; 1.3502x over previous
//
#include <hip/hip_runtime.h>

typedef unsigned short ushort_t;
typedef __attribute__((ext_vector_type(8))) __bf16 bf16x8;
typedef __attribute__((ext_vector_type(8))) short short8_t;
typedef __attribute__((ext_vector_type(4))) short short4_t;
typedef __attribute__((ext_vector_type(4))) float f32x4;

#define C127 (127.0f / 128.0f)

__device__ inline ushort_t f2bf(float f) {
  unsigned u = __builtin_bit_cast(unsigned, f);
  u += 0x7fffu + ((u >> 16) & 1u);
  return (ushort_t)(u >> 16);
}
__device__ inline bf16x8 ldfrag(const ushort_t* p) {
  return __builtin_bit_cast(bf16x8, *(const short8_t*)p);
}
__device__ inline f32x4 mfma16(bf16x8 a, bf16x8 b, f32x4 c) {
  return __builtin_amdgcn_mfma_f32_16x16x32_bf16(a, b, c, 0, 0, 0);
}
// (row,col) -> position in 64-wide swizzled tile
__device__ inline int swz(int row, int col) {
  return row * 64 + (col ^ ((row & 7) << 3));
}
__device__ inline void gl_lds16(const ushort_t* g, ushort_t* l) {
  __builtin_amdgcn_global_load_lds(
      (const __attribute__((address_space(1))) unsigned*)(g),
      (__attribute__((address_space(3))) unsigned*)(l),
      16, 0, 0);
}

// ================= prep: fully vectorized (16B per thread) =================
// wft: per s: [32 rowtiles(64 wcols)][nk kblks][64x64 swz]
// xbt: [32 rowblk][12 kblk][128x64 swz]
// bfm: [8 nb][14 kblk][32x64 swz]
// w1b: row-major [4][16][1024]
__global__ __launch_bounds__(256) void k_prep(
    const float* __restrict__ x,
    const float* Wp, const float* Wmi, const float* Wma, const float* Wd,
    const float* W1p, const float* W1mi, const float* W1ma, const float* W1d,
    const float* Wop, const float* Womi, const float* Woma, const float* Wod,
    const float* bop, const float* bomi, const float* boma, const float* bod,
    const float* Wc,
    ushort_t* wft, ushort_t* xbt, ushort_t* bfm, ushort_t* w1b, float* biassum)
{
  int i = blockIdx.x * 256 + threadIdx.x;
  const int RW = 294912, RX = RW + 393216, RB = RX + 28672, R1 = RB + 8192,
            RE = R1 + 32;
  if (i < RW) {
    const float* src; int base, d, nk;
    if (i < 32768)       { base = 0;      d = 128; nk = 2; src = Wp; }
    else if (i < 98304)  { base = 32768;  d = 256; nk = 4; src = Wmi; }
    else if (i < 196608) { base = 98304;  d = 384; nk = 6; src = Wma; }
    else                 { base = 196608; d = 384; nk = 6; src = Wd; }
    int jl = i - base;
    int tile = jl >> 9, trow = (jl & 511) >> 3, scol0 = (jl & 7) * 8;
    int rowtile = tile / nk, kblk = tile - rowtile * nk;
    int col0 = scol0 ^ ((trow & 7) << 3);
    const float* sp = src + (size_t)(rowtile * 64 + trow) * d + kblk * 64 + col0;
    ushort_t tmp[8];
#pragma unroll
    for (int e = 0; e < 8; ++e) tmp[e] = f2bf(sp[e]);
    *(short8_t*)(wft + (size_t)i * 8) = *(const short8_t*)tmp;
  } else if (i < RX) {
    int i2 = i - RW;
    int tile = i2 >> 10, trow = (i2 & 1023) >> 3, scol0 = (i2 & 7) * 8;
    int rowblk = tile / 12, kblk = tile - rowblk * 12;
    int col0 = scol0 ^ ((trow & 7) << 3);
    const float* sp = x + (size_t)(rowblk * 128 + trow) * 768 + kblk * 64 + col0;
    ushort_t tmp[8];
#pragma unroll
    for (int e = 0; e < 8; ++e) tmp[e] = f2bf(sp[e]);
    *(short8_t*)(xbt + (size_t)i2 * 8) = *(const short8_t*)tmp;
  } else if (i < RB) {
    int i3 = i - RX;
    int tile = i3 >> 8, trow = (i3 & 255) >> 3, scol0 = (i3 & 7) * 8;
    int nb = tile / 14, kblk = tile - nb * 14;
    int col0 = scol0 ^ ((trow & 7) << 3);
    int n = nb * 32 + trow, c0 = kblk * 64 + col0;
    const float* sp;
    if (c0 < 128) {
      int ss = c0 >> 5, jj = c0 & 31;
      const float* src = (ss == 0) ? Wop : (ss == 1) ? Womi : (ss == 2) ? Woma : Wod;
      sp = src + n * 32 + jj;
    } else {
      sp = Wc + n * 768 + (c0 - 128);
    }
    ushort_t tmp[8];
#pragma unroll
    for (int e = 0; e < 8; ++e) tmp[e] = f2bf(sp[e]);
    *(short8_t*)(bfm + (size_t)i3 * 8) = *(const short8_t*)tmp;
  } else if (i < R1) {
    int i4 = i - RB;
    int s = i4 >> 11, r = i4 & 2047;
    const float* src = (s == 0) ? W1p : (s == 1) ? W1mi : (s == 2) ? W1ma : W1d;
    ushort_t tmp[8];
#pragma unroll
    for (int e = 0; e < 8; ++e) tmp[e] = f2bf(src[r * 8 + e]);
    *(short8_t*)(w1b + (size_t)i4 * 8) = *(const short8_t*)tmp;
  } else if (i < RE) {
    int i5 = i - R1;
#pragma unroll
    for (int e = 0; e < 8; ++e) {
      int n = i5 * 8 + e;
      biassum[n] = bop[n] + bomi[n] + boma[n] + bod[n];
    }
  }
}

// == ft GEMM: 8 waves, dbuf, 1-barrier K-steps, balanced 4-s chain/block ==
struct FtP {
  const ushort_t* xbt;
  const ushort_t* wft;
  const ushort_t* w1b;
  float* pf;   // [4 s * 16 g][4096 rows][16 j]
  const float* bft0; const float* bft1; const float* bft2; const float* bft3;
};

__global__ __launch_bounds__(512, 4) void k_ft(FtP p) {
  int bid = blockIdx.x;
  // XCD-aware swizzle (512 = 8 XCD * 64): XCD x gets 4 complete rowblks
  int w = (bid & 7) * 64 + (bid >> 3);
  int g = w & 15, rowblk = w >> 4;
  int row0 = rowblk * 128;
  int tid = threadIdx.x, lane = tid & 63, wid = tid >> 6;
  int wr = wid >> 1, wc = wid & 1;
  int lr = lane & 15, lk = (lane >> 4) * 8, lrow = (lane >> 4) * 4;

  __shared__ ushort_t lA[2][8192];
  __shared__ ushort_t lB[2][2][4096];

  // per-s constant tables (fold after jj-unroll)
  const int S_ORD[4] = {2, 3, 1, 0};
  const int NKA[4] = {2, 4, 6, 6};
  const int SOFF[4] = {0, 262144, 786432, 1572864};
  const unsigned long long CT[4] = {0x60ULL, 0x8721ULL, 0xBA9543ULL, 0xBA8542ULL};
  const float* BFT[4] = {p.bft0, p.bft1, p.bft2, p.bft3};

#define STG(bufi, s_, ks_)                                                     \
  {                                                                            \
    int ch_ = (int)((CT[s_] >> (4 * (ks_))) & 15ULL);                          \
    const ushort_t* at_ = p.xbt + ((size_t)rowblk * 12 + ch_) * 8192;          \
    const ushort_t* b1t_ =                                                     \
        p.wft + SOFF[s_] + ((size_t)(g * NKA[s_] + (ks_))) * 4096;             \
    const ushort_t* b2t_ =                                                     \
        p.wft + SOFF[s_] + ((size_t)((16 + g) * NKA[s_] + (ks_))) * 4096;      \
    { int off = wid * 512; gl_lds16(at_ + off + lane * 8, &lA[bufi][off]); }   \
    { int off = (8 + wid) * 512;                                               \
      gl_lds16(at_ + off + lane * 8, &lA[bufi][off]); }                        \
    { int off = wid * 512;                                                     \
      gl_lds16(b1t_ + off + lane * 8, &lB[bufi][0][off]);                      \
      gl_lds16(b2t_ + off + lane * 8, &lB[bufi][1][off]); }                    \
  }

  int cur = 0;
  // prologue: first job (s=2) tile 0 into buf 0
  STG(0, 2, 0);

#pragma unroll
  for (int jj = 0; jj < 4; ++jj) {
    const int s = S_ORD[jj];
    const int nk = NKA[s];
    const float* bft = BFT[s];

    f32x4 acc[2][2][2];
#pragma unroll
    for (int h = 0; h < 2; ++h)
#pragma unroll
      for (int m = 0; m < 2; ++m)
#pragma unroll
        for (int n = 0; n < 2; ++n) acc[h][m][n] = (f32x4){0.f, 0.f, 0.f, 0.f};

    for (int t = 0; t < nk; ++t) {
      // wait for buf[cur]'s staging (issued one phase ago), then sync
      asm volatile("s_waitcnt vmcnt(0)" ::: "memory");
      __builtin_amdgcn_sched_barrier(0);
      __builtin_amdgcn_s_barrier();
      // stage next tile into the other buffer (safe: all waves past barrier)
      if (t + 1 < nk) {
        STG(cur ^ 1, s, t + 1);
      } else if (jj < 3) {
        const int sn = S_ORD[jj + 1];
        STG(cur ^ 1, sn, 0);
      }
#pragma unroll
      for (int kk = 0; kk < 64; kk += 32) {
        bf16x8 a[2], bb[2][2];
#pragma unroll
        for (int m = 0; m < 2; ++m)
          a[m] = ldfrag(&lA[cur][swz(wr * 32 + m * 16 + lr, kk + lk)]);
#pragma unroll
        for (int h = 0; h < 2; ++h)
#pragma unroll
          for (int n = 0; n < 2; ++n)
            bb[h][n] = ldfrag(&lB[cur][h][swz(wc * 32 + n * 16 + lr, kk + lk)]);
        __builtin_amdgcn_s_setprio(1);
#pragma unroll
        for (int h = 0; h < 2; ++h)
#pragma unroll
          for (int m = 0; m < 2; ++m)
#pragma unroll
            for (int n = 0; n < 2; ++n)
              acc[h][m][n] = mfma16(a[m], bb[h][n], acc[h][m][n]);
        __builtin_amdgcn_s_setprio(0);
      }
      cur ^= 1;
    }

    // ---- epilogue: all job-ends land at cur==0, act buffer = lA[1]
    // (next job's tile0 is in flight into lA[0]/lB[0]) ----
    __builtin_amdgcn_s_barrier();   // all waves done reading lA[1]/lB[1]
    ushort_t* act = lA[1];
#pragma unroll
    for (int m = 0; m < 2; ++m)
#pragma unroll
      for (int n = 0; n < 2; ++n) {
        int col = wc * 32 + n * 16 + lr;
        float bb1 = bft[g * 64 + col];
        float bb2 = bft[1024 + g * 64 + col];
#pragma unroll
        for (int r = 0; r < 4; ++r) {
          int row = wr * 32 + m * 16 + lrow + r;
          float v = (acc[0][m][n][r] + bb1) * (acc[1][m][n][r] + bb2) * C127;
          act[swz(row, col)] = f2bf(v);
        }
      }
    asm volatile("s_waitcnt lgkmcnt(0)" ::: "memory");
    __builtin_amdgcn_sched_barrier(0);
    __builtin_amdgcn_s_barrier();

    const ushort_t* w1base = p.w1b + s * 16384 + lr * 1024 + g * 64 + lk;
    bf16x8 bw0 = ldfrag(w1base);
    bf16x8 bw1 = ldfrag(w1base + 32);
    int rowbase = wid * 16;
    f32x4 facc = {0.f, 0.f, 0.f, 0.f};
    bf16x8 fa0 = ldfrag(&act[swz(rowbase + lr, 0 + lk)]);
    bf16x8 fa1 = ldfrag(&act[swz(rowbase + lr, 32 + lk)]);
    facc = mfma16(fa0, bw0, facc);
    facc = mfma16(fa1, bw1, facc);
    float* pfp =
        p.pf + ((size_t)(s * 16 + g) * 4096 + row0 + rowbase + lrow) * 16 + lr;
#pragma unroll
    for (int r = 0; r < 4; ++r) pfp[r * 16] = facc[r];
    // no trailing barrier: next K-step's barrier orders act reads vs. writes
  }
#undef STG
}

// ============ reduce 16 partials -> cat (vectorized float4/short4) ============
__global__ __launch_bounds__(256) void k_fin(
    const float* __restrict__ pf, ushort_t* __restrict__ cat_t,
    const float* b1p, const float* b1mi, const float* b1ma, const float* b1d)
{
  int tid = threadIdx.x;
  int q = tid & 3, s = (tid >> 2) & 3, rl = tid >> 4;   // 4 x 4 x 16
  int row = blockIdx.x * 16 + rl;
  int j0 = q * 4;
  const float* b1 = (s == 0) ? b1p : (s == 1) ? b1mi : (s == 2) ? b1ma : b1d;
  f32x4 acc = {0.f, 0.f, 0.f, 0.f};
  const float* base = pf + ((size_t)(s * 16) * 4096 + row) * 16 + j0;
#pragma unroll
  for (int g = 0; g < 16; ++g) {
    f32x4 v = *(const f32x4*)(base + (size_t)g * 65536);
    acc += v;
  }
  ushort_t c4f[4], c4s[4];
#pragma unroll
  for (int e = 0; e < 4; ++e) {
    float f = acc[e] + b1[j0 + e];
    c4f[e] = f2bf(fminf(fmaxf(f, 0.f), 1.f));
    c4s[e] = f2bf(fminf(f * f * C127, 1.f));
  }
  int rb = row >> 6, trow = row & 63;
  int c1 = s * 32 + j0;
  {
    int kc = c1 >> 6, tc = (c1 & 63) ^ ((trow & 7) << 3);
    *(short4_t*)&cat_t[(size_t)(rb * 2 + kc) * 4096 + trow * 64 + tc] =
        *(const short4_t*)c4f;
  }
  {
    int c2 = c1 + 16;
    int kc = c2 >> 6, tc = (c2 & 63) ^ ((trow & 7) << 3);
    *(short4_t*)&cat_t[(size_t)(rb * 2 + kc) * 4096 + trow * 64 + tc] =
        *(const short4_t*)c4s;
  }
}

// ======== final GEMM: 64-row blocks, 3-deep pipeline, counted vmcnt ========
__global__ __launch_bounds__(256) void k_out(
    const ushort_t* __restrict__ cat_t, const ushort_t* __restrict__ xbt,
    const ushort_t* __restrict__ bfm, const float* __restrict__ biassum,
    float* __restrict__ out)
{
  int bid = blockIdx.y * 8 + blockIdx.x;
  // XCD-aware swizzle (512 = 8 * 64): XCD x gets 8 complete rowblks
  int w = (bid & 7) * 64 + (bid >> 3);
  int nb = w & 7, rowblk = w >> 3;
  int tid = threadIdx.x, lane = tid & 63, wid = tid >> 6;
  int lr = lane & 15, lk = (lane >> 4) * 8, lrow = (lane >> 4) * 4;

  __shared__ ushort_t lA[3][4096];
  __shared__ ushort_t lB[3][2048];

  f32x4 acc[2];
  acc[0] = (f32x4){0.f, 0.f, 0.f, 0.f};
  acc[1] = (f32x4){0.f, 0.f, 0.f, 0.f};

#define STGO(bufi, kb_)                                                       \
  {                                                                           \
    int kb__ = (kb_);                                                         \
    const ushort_t* at = (kb__ < 2)                                           \
        ? cat_t + ((size_t)rowblk * 2 + kb__) * 4096                          \
        : xbt + ((size_t)(rowblk >> 1) * 12 + (kb__ - 2)) * 8192 +            \
              (rowblk & 1) * 4096;                                            \
    const ushort_t* bt = bfm + ((size_t)nb * 14 + kb__) * 2048;               \
    _Pragma("unroll") for (int c = 0; c < 2; ++c) {                           \
      int off = (c * 4 + wid) * 512;                                          \
      gl_lds16(at + off + lane * 8, &lA[bufi][off]);                          \
    }                                                                         \
    { int off = wid * 512; gl_lds16(bt + off + lane * 8, &lB[bufi][off]); }   \
  }

  STGO(0, 0);
  STGO(1, 1);
  for (int kb = 0; kb < 14; ++kb) {
    int cur = kb % 3;
    if (kb + 1 < 14) {
      asm volatile("s_waitcnt vmcnt(3)" ::: "memory");
    } else {
      asm volatile("s_waitcnt vmcnt(0)" ::: "memory");
    }
    __builtin_amdgcn_sched_barrier(0);
    __builtin_amdgcn_s_barrier();
    if (kb + 2 < 14) STGO((kb + 2) % 3, kb + 2);
#pragma unroll
    for (int kk = 0; kk < 64; kk += 32) {
      bf16x8 b0 = ldfrag(&lB[cur][swz(lr, kk + lk)]);
      bf16x8 b1v = ldfrag(&lB[cur][swz(16 + lr, kk + lk)]);
      bf16x8 a = ldfrag(&lA[cur][swz(wid * 16 + lr, kk + lk)]);
      __builtin_amdgcn_s_setprio(1);
      acc[0] = mfma16(a, b0, acc[0]);
      acc[1] = mfma16(a, b1v, acc[1]);
      __builtin_amdgcn_s_setprio(0);
    }
    // no trailing barrier: buf reuse is 2 steps away, ordered by next barrier
  }
#undef STGO

#pragma unroll
  for (int n = 0; n < 2; ++n) {
    int col = nb * 32 + n * 16 + lr;
    float bs = biassum[col];
#pragma unroll
    for (int r = 0; r < 4; ++r) {
      int row = rowblk * 64 + wid * 16 + lrow + r;
      out[(size_t)row * 256 + col] = acc[n][r] + bs;
    }
  }
}

extern "C" void kernel_launch(void* const* d_in, const int* in_sizes, int n_in,
                              void* d_out, int out_size, void* d_ws, size_t ws_size,
                              hipStream_t stream)
{
  const float* x     = (const float*)d_in[0];
  const float* pWft  = (const float*)d_in[5];   const float* pbft  = (const float*)d_in[6];
  const float* pW1   = (const float*)d_in[7];   const float* pb1   = (const float*)d_in[8];
  const float* pWo   = (const float*)d_in[9];   const float* pbo   = (const float*)d_in[10];
  const float* miWft = (const float*)d_in[11];  const float* mibft = (const float*)d_in[12];
  const float* miW1  = (const float*)d_in[13];  const float* mib1  = (const float*)d_in[14];
  const float* miWo  = (const float*)d_in[15];  const float* mibo  = (const float*)d_in[16];
  const float* maWft = (const float*)d_in[17];  const float* mabft = (const float*)d_in[18];
  const float* maW1  = (const float*)d_in[19];  const float* mab1  = (const float*)d_in[20];
  const float* maWo  = (const float*)d_in[21];  const float* mabo  = (const float*)d_in[22];
  const float* dWft  = (const float*)d_in[23];  const float* dbft  = (const float*)d_in[24];
  const float* dW1   = (const float*)d_in[25];  const float* db1   = (const float*)d_in[26];
  const float* dWo   = (const float*)d_in[27];  const float* dbo   = (const float*)d_in[28];
  const float* Wc    = (const float*)d_in[29];

  char* wsb = (char*)d_ws;
  ushort_t* xbt     = (ushort_t*)(wsb + 0);          //  6,291,456
  ushort_t* wft     = (ushort_t*)(wsb + 6291456);    //  4,718,592
  ushort_t* w1b     = (ushort_t*)(wsb + 11010048);   //    131,072
  ushort_t* bfm     = (ushort_t*)(wsb + 11141120);   //    458,752
  float*    biassum = (float*)(wsb + 11599872);      //      1,024
  float*    pf      = (float*)(wsb + 11600896);      // 16,777,216
  ushort_t* cat_t   = (ushort_t*)(wsb + 28378112);   //  1,048,576

  k_prep<<<dim3(2833), dim3(256), 0, stream>>>(
      x, pWft, miWft, maWft, dWft, pW1, miW1, maW1, dW1,
      pWo, miWo, maWo, dWo, pbo, mibo, mabo, dbo, Wc,
      wft, xbt, bfm, w1b, biassum);

  FtP fp;
  fp.xbt = xbt; fp.wft = wft; fp.w1b = w1b; fp.pf = pf;
  fp.bft0 = pbft; fp.bft1 = mibft; fp.bft2 = mabft; fp.bft3 = dbft;
  k_ft<<<dim3(512), dim3(512), 0, stream>>>(fp);

  k_fin<<<dim3(256), dim3(256), 0, stream>>>(pf, cat_t, pb1, mib1, mab1, db1);

  k_out<<<dim3(8, 64), dim3(256), 0, stream>>>(cat_t, xbt, bfm, biassum, (float*)d_out);
}